// Round 4
// baseline (260.799 us; speedup 1.0000x reference)
//
#include <hip/hip_runtime.h>
#include <hip/hip_bf16.h>

// Problem: B=2, DIM=512, NUM_HEADS=1, tokens TOK=256 (16x16 window, w=1).
// SINGLE persistent kernel, 512 blocks x 256 threads (co-resident: 2 blocks/CU,
// __launch_bounds__(256,2) caps VGPR<=256, LDS union ~40KB <= 80KB/block).
// Phases separated by device-scope software barriers:
//   P1 qkv gemm (BM=192, Ksplit=8)  -> qkvp[16 z][1536][256]
//   P2 fused per-channel attention  -> aout[2][512][256]
//   P3 proj gemm (BM=64, Ksplit=8)  -> projp[16 z][512][256]
//   P4 combine 8 parts + proj bias  -> out
// Barrier counters in ws bytes [0,256), zeroed each call by hipMemsetAsync
// (ws is re-poisoned 0xAA by the harness; memset makes init deterministic).
// Float data starts at ws+64 floats.

#define TOK   256
#define KDIM  512
#define LOG2E 1.4426950408889634f
#define SCALE 0.04419417382415922f   // 512^{-1/2}
#define NPART 8
#define QPSTRIDE 786432              // 2*1536*256: qkv ks-part stride (fixed b)
#define PPSTRIDE 262144              // 2*512*256 : proj ks-part stride (fixed b)
#define NBLK  512

// v_exp_f32 (base-2) — __exp2f collides with glibc math.h, use the builtin.
#define EXP2(x) __builtin_amdgcn_exp2f(x)

union Smem {
    struct { float As[2][16][196]; float Bs[2][16][64]; } g1;   // 33.3 KB
    struct { float As[2][16][68];  float Bs[2][16][64]; } g3;   // 16.7 KB
    struct {
        float ks_[2][TOK], vs_[2][TOK];
        float tab2[64];
        float brow[31][258];
        float lpart[2][TOK], apart[2][TOK];
    } at;                                                       // 40.4 KB
};

// Device-scope grid barrier. Release: __threadfence (wb L2) + AGENT atomic add.
// Spin with RMW (fetch_add 0) so the poll always reaches the coherent point
// (a relaxed load could be served stale from the local XCD L2 -> deadlock).
// Acquire: __threadfence after the spin, before any cross-block data reads.
__device__ __forceinline__ void gbar(int* cnt)
{
    __syncthreads();                  // all block threads done; vmcnt drained
    if (threadIdx.x == 0) {
        __threadfence();              // make this block's stores visible (wb)
        __hip_atomic_fetch_add(cnt, 1, __ATOMIC_RELAXED, __HIP_MEMORY_SCOPE_AGENT);
        while (__hip_atomic_fetch_add(cnt, 0, __ATOMIC_RELAXED,
                                      __HIP_MEMORY_SCOPE_AGENT) < NBLK)
            __builtin_amdgcn_s_sleep(2);
        __threadfence();              // acquire side (inv) before data reads
    }
    __syncthreads();
}

// fp32 GEMM phase: C[BM x 64] = A[BM x 64 k-slice] @ B[64 k-slice x 64].
// Double-buffered LDS, 1 barrier/iter, register prefetch distance 1.
// BM=192: MM=12 (3x b128 A-frag reads, conflict-free); BM=64: MM=4.
template<int BM, int KLEN>
__device__ __forceinline__ void gemm_dev(const float* __restrict__ Ab,
                                         const float* __restrict__ Bb,
                                         float* __restrict__ Cb,
                                         float* sA, float* sB)
{
    constexpr int NITER = KLEN / 16;
    constexpr int MM    = BM / 16;
    constexpr int SEG   = BM / 64;
    constexpr int LDA   = BM + 4;     // transpose-store 2-way max (free)

    const int t   = threadIdx.x;
    const int ar  = t >> 2;           // A row within 64-row segment
    const int ac4 = (t & 3) * 4;      // A k-quad
    const int bk  = t >> 4;           // B k-row
    const int bn4 = (t & 15) * 4;     // B n-quad
    const int m0  = (t >> 4) * MM;
    const int n4  = (t & 15) * 4;

    float4 ra[SEG], rb;
    auto LOAD = [&](int it) {
        const int k0 = it * 16;
#pragma unroll
        for (int s = 0; s < SEG; ++s)
            ra[s] = *(const float4*)(Ab + (size_t)(s * 64 + ar) * KDIM + k0 + ac4);
        rb = *(const float4*)(Bb + (size_t)(k0 + bk) * TOK + bn4);
    };
    auto STORE = [&](int buf) {
        float* As = sA + buf * 16 * LDA;
#pragma unroll
        for (int s = 0; s < SEG; ++s) {
            As[(ac4 + 0) * LDA + s * 64 + ar] = ra[s].x;
            As[(ac4 + 1) * LDA + s * 64 + ar] = ra[s].y;
            As[(ac4 + 2) * LDA + s * 64 + ar] = ra[s].z;
            As[(ac4 + 3) * LDA + s * 64 + ar] = ra[s].w;
        }
        *(float4*)(sB + buf * 16 * 64 + bk * 64 + bn4) = rb;
    };

    float acc[MM][4];
#pragma unroll
    for (int i = 0; i < MM; ++i)
#pragma unroll
        for (int j = 0; j < 4; ++j) acc[i][j] = 0.f;

    LOAD(0); STORE(0);
    if (NITER > 1) LOAD(1);
    __syncthreads();

#pragma unroll
    for (int it = 0; it < NITER; ++it) {
        const int cur = it & 1;
        if (it + 1 < NITER) STORE(1 - cur);
        if (it + 2 < NITER) LOAD(it + 2);
        const float* As = sA + cur * 16 * LDA;
        const float* Bs = sB + cur * 16 * 64;
#pragma unroll
        for (int kk = 0; kk < 16; ++kk) {
            const float4 b4 = *(const float4*)(Bs + kk * 64 + n4);
            float af[MM];
#pragma unroll
            for (int mi = 0; mi < MM; mi += 4) {
                const float4 a4 = *(const float4*)(As + kk * LDA + m0 + mi);
                af[mi + 0] = a4.x; af[mi + 1] = a4.y;
                af[mi + 2] = a4.z; af[mi + 3] = a4.w;
            }
#pragma unroll
            for (int mi = 0; mi < MM; ++mi) {
                acc[mi][0] = fmaf(af[mi], b4.x, acc[mi][0]);
                acc[mi][1] = fmaf(af[mi], b4.y, acc[mi][1]);
                acc[mi][2] = fmaf(af[mi], b4.z, acc[mi][2]);
                acc[mi][3] = fmaf(af[mi], b4.w, acc[mi][3]);
            }
        }
        __syncthreads();
    }

#pragma unroll
    for (int mi = 0; mi < MM; ++mi)
        *(float4*)(Cb + (size_t)(m0 + mi) * TOK + n4) =
            make_float4(acc[mi][0], acc[mi][1], acc[mi][2], acc[mi][3]);
}

__global__ __launch_bounds__(256, 2)
void fused_attn(const float* __restrict__ x, const float* __restrict__ qkv_w,
                const float* __restrict__ qkv_b, const float* __restrict__ proj_w,
                const float* __restrict__ proj_b, const float* __restrict__ rpb,
                float* __restrict__ out, float* __restrict__ ws)
{
    __shared__ Smem sm;
    const int blk = blockIdx.x;
    const int t   = threadIdx.x;

    int*   bar   = (int*)ws;            // bytes [0,256): 3 barrier counters
    float* qkvp  = ws + 64;             // 16 z * 1536*256 = 6,291,456 floats
    float* aoutp = qkvp + 6291456;      // 262,144 floats
    float* projp = aoutp + 262144;      // 16 z * 512*256 = 2,097,152 floats

    // ---------------- P1: qkv gemm (BM=192, BN=64, Ksplit=8) ----------------
    {
        const int nt = blk & 3, mt = (blk >> 2) & 7, z = blk >> 5;
        const int b = z & 1, ks = z >> 1;
        gemm_dev<192, 64>(qkv_w + (size_t)(mt * 192) * KDIM + ks * 64,
                          x + ((size_t)b * KDIM + ks * 64) * TOK + nt * 64,
                          qkvp + ((size_t)z * 1536 + mt * 192) * TOK + nt * 64,
                          &sm.g1.As[0][0][0], &sm.g1.Bs[0][0][0]);
    }
    gbar(bar + 0);

    // ---------------- P2: fused per-channel attention -----------------------
    {
        const int b  = blk >> 8;
        const int d0 = (blk & 255) * 2;
        const float* q0 = qkvp + (size_t)b * (1536 * TOK);

        if (t < 61) {
            const int rel = t - 30;
            sm.at.tab2[t] = rpb[rel < 0 ? rel + 961 : rel] * LOG2E;
        }
        {   // stage k (pre-scaled) and v: sum 8 K-split parts + qkv bias
            const int sel = t >> 7;
            const int row = (t >> 6) & 1;
            const int g4  = (t & 63) * 4;
            const int o   = (sel ? 1024 : 512) + d0 + row;
            const float* p = q0 + (size_t)o * TOK + g4;
            const float bb = qkv_b[o];
            float4 v = make_float4(bb, bb, bb, bb);
#pragma unroll
            for (int pp = 0; pp < NPART; ++pp) {
                const float4 xv = *(const float4*)(p + (size_t)pp * QPSTRIDE);
                v.x += xv.x; v.y += xv.y; v.z += xv.z; v.w += xv.w;
            }
            if (sel == 0) {
                const float s = SCALE * LOG2E;
                v.x *= s; v.y *= s; v.z *= s; v.w *= s;
                *(float4*)&sm.at.ks_[row][g4] = v;
            } else {
                *(float4*)&sm.at.vs_[row][g4] = v;
            }
        }
        __syncthreads();
        {   // replicate 61-entry bias table into 31 rows x 256 g
            const int rg = ((t >> 4) & 15) + (t & 15);
#pragma unroll 1
            for (int it = 0; it < 31; ++it)
                sm.at.brow[it][t] = sm.at.tab2[it - rg + 30];
        }
        __syncthreads();

        const int w   = t >> 6;
        const int dl  = w & 1;
        const int gh  = w >> 1;
        const int hl  = t & 63;
        const int qi  = ((hl & 15) << 2) | (hl >> 4);
        const int h0  = qi * 4;
        const int rh0 = (qi >> 2) + 4 * (qi & 3);

        float q[4];
        {
            const float* p = q0 + (size_t)(d0 + dl) * TOK + h0;
            const float bb = qkv_b[d0 + dl];
            q[0] = bb; q[1] = bb; q[2] = bb; q[3] = bb;
#pragma unroll
            for (int pp = 0; pp < NPART; ++pp) {
                const float4 xv = *(const float4*)(p + (size_t)pp * QPSTRIDE);
                q[0] += xv.x; q[1] += xv.y; q[2] += xv.z; q[3] += xv.w;
            }
        }

        float l[4]  = {0.f, 0.f, 0.f, 0.f};
        float am[4] = {0.f, 0.f, 0.f, 0.f};
        const int pbeg = gh * 128;
#pragma unroll 2
        for (int p = pbeg; p < pbeg + 128; p += 4) {
            const float4 k4 = *(const float4*)&sm.at.ks_[dl][p];
            const float4 v4 = *(const float4*)&sm.at.vs_[dl][p];
#pragma unroll
            for (int r = 0; r < 4; ++r) {
                const float2 b01 = *(const float2*)&sm.at.brow[rh0 + r][p];
                const float2 b23 = *(const float2*)&sm.at.brow[rh0 + r][p + 2];
                float e;
                e = EXP2(fmaf(q[r], k4.x, b01.x)); l[r] += e; am[r] = fmaf(e, v4.x, am[r]);
                e = EXP2(fmaf(q[r], k4.y, b01.y)); l[r] += e; am[r] = fmaf(e, v4.y, am[r]);
                e = EXP2(fmaf(q[r], k4.z, b23.x)); l[r] += e; am[r] = fmaf(e, v4.z, am[r]);
                e = EXP2(fmaf(q[r], k4.w, b23.y)); l[r] += e; am[r] = fmaf(e, v4.w, am[r]);
            }
        }

        if (gh == 1) {
            *(float4*)&sm.at.lpart[dl][h0] = make_float4(l[0], l[1], l[2], l[3]);
            *(float4*)&sm.at.apart[dl][h0] = make_float4(am[0], am[1], am[2], am[3]);
        }
        __syncthreads();
        if (gh == 0) {
            const float4 lo = *(const float4*)&sm.at.lpart[dl][h0];
            const float4 ao = *(const float4*)&sm.at.apart[dl][h0];
            float4 o4;
            o4.x = (am[0] + ao.x) / (l[0] + lo.x);
            o4.y = (am[1] + ao.y) / (l[1] + lo.y);
            o4.z = (am[2] + ao.z) / (l[2] + lo.z);
            o4.w = (am[3] + ao.w) / (l[3] + lo.w);
            *(float4*)(aoutp + ((size_t)b * 512 + d0 + dl) * TOK + h0) = o4;
        }
    }
    gbar(bar + 1);

    // ---------------- P3: proj gemm (BM=64, BN=64, Ksplit=8) ----------------
    {
        const int nt = blk & 3, mt = (blk >> 2) & 7, z = blk >> 5;
        const int b = z & 1, ks = z >> 1;
        gemm_dev<64, 64>(proj_w + (size_t)(mt * 64) * KDIM + ks * 64,
                         aoutp + ((size_t)b * KDIM + ks * 64) * TOK + nt * 64,
                         projp + ((size_t)z * 512 + mt * 64) * TOK + nt * 64,
                         &sm.g3.As[0][0][0], &sm.g3.Bs[0][0][0]);
    }
    gbar(bar + 2);

    // ---------------- P4: combine 8 proj parts + bias -----------------------
    {
        const int flat2 = (blk * 256 + t) * 2;
        const int o = (flat2 >> 8) & 511;
        const float bb = proj_b[o];
        float2 a = make_float2(bb, bb);
#pragma unroll
        for (int p = 0; p < NPART; ++p) {
            const float2 xv = *(const float2*)(projp + (size_t)p * PPSTRIDE + flat2);
            a.x += xv.x; a.y += xv.y;
        }
        *(float2*)(out + flat2) = a;
    }
}

// ---------------------------------------------------------------------------
extern "C" void kernel_launch(void* const* d_in, const int* in_sizes, int n_in,
                              void* d_out, int out_size, void* d_ws, size_t ws_size,
                              hipStream_t stream)
{
    const float* x      = (const float*)d_in[0];   // [2][512][256]
    const float* qkv_w  = (const float*)d_in[1];   // [1536][512]
    const float* qkv_b  = (const float*)d_in[2];   // [1536]
    const float* proj_w = (const float*)d_in[3];   // [512][512]
    const float* proj_b = (const float*)d_in[4];   // [512]
    const float* rpb    = (const float*)d_in[5];   // [961]
    float* out = (float*)d_out;                    // [2][512][256]
    float* ws  = (float*)d_ws;

    // zero the 3 grid-barrier counters (ws is poisoned 0xAA before every call)
    hipMemsetAsync(d_ws, 0, 256, stream);

    fused_attn<<<dim3(NBLK), 256, 0, stream>>>(x, qkv_w, qkv_b, proj_w, proj_b,
                                               rpb, out, ws);
}

// Round 5
// 133.817 us; speedup vs baseline: 1.9489x; 1.9489x over previous
//
#include <hip/hip_runtime.h>
#include <hip/hip_bf16.h>

// Problem: B=2, DIM=512, NUM_HEADS=1, tokens TOK=256 (16x16 window, w=1).
// 4 dispatches (inter-kernel handoff rides the implicit end-of-kernel L2
// flush -> L3; R4 showed explicit fences at low occupancy force HBM = 2.5x
// slower):
//   [qkv gemm BM=96 ks=4, 512 blocks] -> [attention, sums 4 parts]
//   -> [proj gemm BM=64 ks=4, 256 blocks] -> [combine 4 parts + bias]
// Workspace (floats):
//   qkvp  = ws + 0        : 8 z(ks*2+b) * [1536][256] = 3,145,728  (12 MB)
//   aout  = ws + 3145728  : [2][512][256]             =   262,144
//   projp = ws + 3407872  : 8 z(ks*2+b) * [512][256]  = 1,048,576  (4 MB)

#define TOK   256
#define KDIM  512
#define LOG2E 1.4426950408889634f
#define SCALE 0.04419417382415922f   // 512^{-1/2}
#define NPART 4
#define QPSTRIDE 786432              // 2*1536*256: qkv part stride (fixed b)
#define PPSTRIDE 262144              // 2*512*256 : proj part stride (fixed b)

// v_exp_f32 (base-2) — __exp2f collides with glibc math.h, use the builtin.
#define EXP2(x) __builtin_amdgcn_exp2f(x)

// ---------------------------------------------------------------------------
// fp32 GEMM, K-split, double-buffered LDS, register prefetch distance 1.
// Cpart[z=(ks*2+b)][M][TOK] = A[Mtile x KLEN] @ B[b][KLEN][64ntile]
// BM x 64 tile, BK=32, 256 threads, (BM/16) x 4 microtile.
// LDA=BM+2: transposed A-stores <=2-way (free), float2 frag reads
// conflict-free & 8B-aligned.
// ---------------------------------------------------------------------------
template<int BM, int KLEN, int BK>
__global__ __launch_bounds__(256)
void gemm_f32(const float* __restrict__ A, const float* __restrict__ B,
              float* __restrict__ C, int M)
{
    constexpr int NITER = KLEN / BK;
    constexpr int MM    = BM / 16;          // micro rows/thread (6 or 4)
    constexpr int LDA   = BM + 2;
    constexpr int AL    = BM * BK / 1024;   // float4 A-loads/thread
    constexpr int BL    = 64 * BK / 1024;   // float4 B-loads/thread
    constexpr int QPR   = BK / 4;           // k-quads per A row

    __shared__ float As[2][BK][LDA];        // [buf][k][m] transposed
    __shared__ float Bs[2][BK][64];         // [buf][k][n]

    const int t  = threadIdx.x;
    const int z  = blockIdx.z;              // ks*2 + b
    const int b  = z & 1;
    const int ks = z >> 1;

    const float* Ab = A + (size_t)(blockIdx.x * BM) * KDIM + ks * KLEN;
    const float* Bb = B + ((size_t)b * KDIM + ks * KLEN) * TOK + blockIdx.y * 64;
    float*       Cb = C + ((size_t)z * M + blockIdx.x * BM) * TOK + blockIdx.y * 64;

    // staging maps (compile-time unrolled; QPR is a power of 2)
    int arow[AL], aq[AL], bkr[BL], bq[BL];
#pragma unroll
    for (int i = 0; i < AL; ++i) {
        const int idx = t + 256 * i;
        arow[i] = idx / QPR;
        aq[i]   = (idx % QPR) * 4;
    }
#pragma unroll
    for (int i = 0; i < BL; ++i) {
        const int idx = t + 256 * i;
        bkr[i] = idx >> 4;
        bq[i]  = (idx & 15) * 4;
    }

    float4 ra[AL], rb[BL];
    auto LOAD = [&](int it) {
        const int k0 = it * BK;
#pragma unroll
        for (int i = 0; i < AL; ++i)
            ra[i] = *(const float4*)(Ab + (size_t)arow[i] * KDIM + k0 + aq[i]);
#pragma unroll
        for (int i = 0; i < BL; ++i)
            rb[i] = *(const float4*)(Bb + (size_t)(k0 + bkr[i]) * TOK + bq[i]);
    };
    auto STORE = [&](int buf) {
#pragma unroll
        for (int i = 0; i < AL; ++i) {
            As[buf][aq[i] + 0][arow[i]] = ra[i].x;
            As[buf][aq[i] + 1][arow[i]] = ra[i].y;
            As[buf][aq[i] + 2][arow[i]] = ra[i].z;
            As[buf][aq[i] + 3][arow[i]] = ra[i].w;
        }
#pragma unroll
        for (int i = 0; i < BL; ++i)
            *(float4*)&Bs[buf][bkr[i]][bq[i]] = rb[i];
    };

    const int m0 = (t >> 4) * MM;
    const int n4 = (t & 15) * 4;

    float acc[MM][4];
#pragma unroll
    for (int i = 0; i < MM; ++i)
#pragma unroll
        for (int j = 0; j < 4; ++j) acc[i][j] = 0.f;

    LOAD(0); STORE(0);
    if (NITER > 1) LOAD(1);
    __syncthreads();

#pragma unroll
    for (int it = 0; it < NITER; ++it) {
        const int cur = it & 1;
        if (it + 1 < NITER) STORE(1 - cur);
        if (it + 2 < NITER) LOAD(it + 2);
#pragma unroll
        for (int kk = 0; kk < BK; ++kk) {
            const float4 b4 = *(const float4*)&Bs[cur][kk][n4];
            float af[MM];
#pragma unroll
            for (int mi = 0; mi < MM; mi += 2) {
                const float2 a2 = *(const float2*)&As[cur][kk][m0 + mi];
                af[mi] = a2.x; af[mi + 1] = a2.y;
            }
#pragma unroll
            for (int mi = 0; mi < MM; ++mi) {
                acc[mi][0] = fmaf(af[mi], b4.x, acc[mi][0]);
                acc[mi][1] = fmaf(af[mi], b4.y, acc[mi][1]);
                acc[mi][2] = fmaf(af[mi], b4.z, acc[mi][2]);
                acc[mi][3] = fmaf(af[mi], b4.w, acc[mi][3]);
            }
        }
        __syncthreads();
    }

#pragma unroll
    for (int mi = 0; mi < MM; ++mi)
        *(float4*)(Cb + (size_t)(m0 + mi) * TOK + n4) =
            make_float4(acc[mi][0], acc[mi][1], acc[mi][2], acc[mi][3]);
}

// ---------------------------------------------------------------------------
// Fused per-channel attention (sums the 4 qkv K-split parts inline).
// Block = 256 threads handles (b, d0..d0+1): waves = (dl, g-half).
// bias[h,g] = tab[r(h)-r(g)+30], r(h)=(h>>4)+(h&15): 61 distinct values,
// replicated into brow[31][258] (2-bank step, conflict-free float2 reads).
// Scores bounded (~1.1) -> no max-subtraction; g-half partials merge additively.
// ---------------------------------------------------------------------------
__global__ __launch_bounds__(256)
void attn_f32(const float* __restrict__ qkvp, const float* __restrict__ qkv_b,
              const float* __restrict__ rpb, float* __restrict__ aout)
{
    __shared__ float ks_[2][TOK];      // k * scale * log2e (incl. qkv bias)
    __shared__ float vs_[2][TOK];      // v (incl. qkv bias)
    __shared__ float tab2[64];         // rpb gathered, * log2e
    __shared__ float brow[31][258];    // bias rows, stride 258 (2-bank step)
    __shared__ float lpart[2][TOK];
    __shared__ float apart[2][TOK];

    const int t  = threadIdx.x;
    const int b  = blockIdx.y;
    const int d0 = blockIdx.x * 2;
    const float* q0 = qkvp + (size_t)b * (1536 * TOK);

    if (t < 61) {
        const int rel = t - 30;
        tab2[t] = rpb[rel < 0 ? rel + 961 : rel] * LOG2E;
    }
    {   // stage k (pre-scaled) and v: sum 4 K-split parts + qkv bias
        const int sel = t >> 7;          // 0: k, 1: v
        const int row = (t >> 6) & 1;    // dl
        const int g4  = (t & 63) * 4;
        const int o   = (sel ? 1024 : 512) + d0 + row;
        const float* p = q0 + (size_t)o * TOK + g4;
        const float bb = qkv_b[o];
        float4 v = make_float4(bb, bb, bb, bb);
#pragma unroll
        for (int pp = 0; pp < NPART; ++pp) {
            const float4 xv = *(const float4*)(p + (size_t)pp * QPSTRIDE);
            v.x += xv.x; v.y += xv.y; v.z += xv.z; v.w += xv.w;
        }
        if (sel == 0) {
            const float s = SCALE * LOG2E;
            v.x *= s; v.y *= s; v.z *= s; v.w *= s;
            *(float4*)&ks_[row][g4] = v;
        } else {
            *(float4*)&vs_[row][g4] = v;
        }
    }
    __syncthreads();
    {   // replicate 61-entry bias table into 31 rows x 256 g
        const int rg = ((t >> 4) & 15) + (t & 15);
#pragma unroll 1
        for (int it = 0; it < 31; ++it)
            brow[it][t] = tab2[it - rg + 30];
    }
    __syncthreads();

    const int w   = t >> 6;
    const int dl  = w & 1;
    const int gh  = w >> 1;
    const int hl  = t & 63;
    const int qi  = ((hl & 15) << 2) | (hl >> 4);  // bit-swizzled h-quad index
    const int h0  = qi * 4;
    const int rh0 = (qi >> 2) + 4 * (qi & 3);      // r(h0); r(h0+r)=rh0+r

    float q[4];
    {
        const float* p = q0 + (size_t)(d0 + dl) * TOK + h0;
        const float bb = qkv_b[d0 + dl];
        q[0] = bb; q[1] = bb; q[2] = bb; q[3] = bb;
#pragma unroll
        for (int pp = 0; pp < NPART; ++pp) {
            const float4 xv = *(const float4*)(p + (size_t)pp * QPSTRIDE);
            q[0] += xv.x; q[1] += xv.y; q[2] += xv.z; q[3] += xv.w;
        }
    }

    float l[4]  = {0.f, 0.f, 0.f, 0.f};
    float am[4] = {0.f, 0.f, 0.f, 0.f};
    const int pbeg = gh * 128;
#pragma unroll 2
    for (int p = pbeg; p < pbeg + 128; p += 4) {
        const float4 k4 = *(const float4*)&ks_[dl][p];   // wave-uniform (bcast)
        const float4 v4 = *(const float4*)&vs_[dl][p];
#pragma unroll
        for (int r = 0; r < 4; ++r) {
            const float2 b01 = *(const float2*)&brow[rh0 + r][p];
            const float2 b23 = *(const float2*)&brow[rh0 + r][p + 2];
            float e;
            e = EXP2(fmaf(q[r], k4.x, b01.x)); l[r] += e; am[r] = fmaf(e, v4.x, am[r]);
            e = EXP2(fmaf(q[r], k4.y, b01.y)); l[r] += e; am[r] = fmaf(e, v4.y, am[r]);
            e = EXP2(fmaf(q[r], k4.z, b23.x)); l[r] += e; am[r] = fmaf(e, v4.z, am[r]);
            e = EXP2(fmaf(q[r], k4.w, b23.y)); l[r] += e; am[r] = fmaf(e, v4.w, am[r]);
        }
    }

    if (gh == 1) {
        *(float4*)&lpart[dl][h0] = make_float4(l[0], l[1], l[2], l[3]);
        *(float4*)&apart[dl][h0] = make_float4(am[0], am[1], am[2], am[3]);
    }
    __syncthreads();
    if (gh == 0) {
        const float4 lo = *(const float4*)&lpart[dl][h0];
        const float4 ao = *(const float4*)&apart[dl][h0];
        float4 o4;
        o4.x = (am[0] + ao.x) / (l[0] + lo.x);
        o4.y = (am[1] + ao.y) / (l[1] + lo.y);
        o4.z = (am[2] + ao.z) / (l[2] + lo.z);
        o4.w = (am[3] + ao.w) / (l[3] + lo.w);
        *(float4*)(aout + ((size_t)b * 512 + d0 + dl) * TOK + h0) = o4;
    }
}

// ---------------------------------------------------------------------------
// Sum the 4 proj K-split parts + proj bias -> final output [2][512][256].
// flat already encodes b (bit 17); z = 2p + b handled by p*PPSTRIDE + flat.
// ---------------------------------------------------------------------------
__global__ __launch_bounds__(256)
void combine_f32(const float* __restrict__ pp, const float* __restrict__ pb,
                 float* __restrict__ out)
{
    const int flat = (blockIdx.x * 256 + threadIdx.x) * 4;
    const int o = (flat >> 8) & 511;
    const float bb = pb[o];
    float4 a = make_float4(bb, bb, bb, bb);
#pragma unroll
    for (int p = 0; p < NPART; ++p) {
        const float4 x = *(const float4*)(pp + (size_t)p * PPSTRIDE + flat);
        a.x += x.x; a.y += x.y; a.z += x.z; a.w += x.w;
    }
    *(float4*)(out + flat) = a;
}

// ---------------------------------------------------------------------------
extern "C" void kernel_launch(void* const* d_in, const int* in_sizes, int n_in,
                              void* d_out, int out_size, void* d_ws, size_t ws_size,
                              hipStream_t stream)
{
    const float* x      = (const float*)d_in[0];   // [2][512][256]
    const float* qkv_w  = (const float*)d_in[1];   // [1536][512]
    const float* qkv_b  = (const float*)d_in[2];   // [1536]
    const float* proj_w = (const float*)d_in[3];   // [512][512]
    const float* proj_b = (const float*)d_in[4];   // [512]
    const float* rpb    = (const float*)d_in[5];   // [961]
    float* out = (float*)d_out;                    // [2][512][256]
    float* ws  = (float*)d_ws;

    float* qkvp  = ws;                 // 8 z * 393216
    float* aout  = ws + 3145728;       // 262144
    float* projp = ws + 3407872;       // 8 z * 131072

    // qkv: M=1536, BM=96, ks=4 -> grid (16,4,8) = 512 blocks (2/CU, balanced)
    gemm_f32<96, 128, 32><<<dim3(16, 4, 8), 256, 0, stream>>>(qkv_w, x, qkvp, 1536);

    // attention: grid (d-pairs=256, b=2) = 512 blocks
    attn_f32<<<dim3(256, 2), 256, 0, stream>>>(qkvp, qkv_b, rpb, aout);

    // proj: M=512, BM=64, ks=4 -> grid (8,4,8) = 256 blocks (1/CU, balanced)
    gemm_f32<64, 128, 32><<<dim3(8, 4, 8), 256, 0, stream>>>(proj_w, aout, projp, 512);

    // sum 4 parts + bias
    combine_f32<<<dim3(256), 256, 0, stream>>>(projp, proj_b, out);
}

// Round 6
// 110.353 us; speedup vs baseline: 2.3633x; 1.2126x over previous
//
#include <hip/hip_runtime.h>
#include <hip/hip_bf16.h>

// Problem: B=2, DIM=512, NUM_HEADS=1, tokens TOK=256 (16x16 window, w=1).
// R5 showed the pipeline is bound by intermediate-tensor HBM round-trips
// (qkvp 12 MB w+r, projp 4 MB w+r at ~420 GB/s effective ~= 75 us), not FLOPs.
// This round: exploit per-channel independence to kill ALL intermediates
// except aout (1 MB):
//   K1 (512 blocks = b x d-pair): computes its OWN 6 qkv rows (K=512 GEMM,
//       weights via wave-uniform s_loads, x streamed from L2, 4-wave c-split
//       + LDS reduce), then runs the R3 attention phase in-block. -> aout.
//   K2 (256 blocks = b x 4-out-rows): proj GEMM with 4-wave c-split + LDS
//       reduce + bias -> writes d_out directly.
// Workspace: aout only (262,144 floats = 1 MB).

#define TOK   256
#define KDIM  512
#define LOG2E 1.4426950408889634f
#define SCALE 0.04419417382415922f   // 512^{-1/2}

// v_exp_f32 (base-2) — __exp2f collides with glibc math.h, use the builtin.
#define EXP2(x) __builtin_amdgcn_exp2f(x)

// ---------------------------------------------------------------------------
// K1: fused qkv-gemm + per-channel attention.
// Block (dp, b): channels d0=2*dp, d0+1. 256 threads = 4 waves.
// GEMM phase: wave w owns c-quarter [128w,128w+128); lane owns g-quad.
//   acc[e][j], e: 0,1=q(d0,d0+1) 2,3=k 4,5=v. W reads are wave-uniform
//   (block+loop indices only) -> s_load; x reads coalesced float4.
// Reduce: red[4][6][256] in LDS, then thread t sums 4 parts for (e, g=t),
//   adds qkv bias, scales k by SCALE*LOG2E, writes ks_/vs_/qs_.
// Attention phase: identical structure to R3 (passed, absmax 9.8e-4):
//   bias[h,g]=tab[r(h)-r(g)+30] replicated to brow[31][258] (2-bank step,
//   ~2-way max = free); waves=(dl,gh); no softmax max-subtraction (scores
//   bounded ~1.1) so g-half partials merge additively via lpart/apart.
// LDS: union{red 24KB | brow 31.2KB} + tab + ks/vs/qs + lpart/apart = 42.5KB.
// ---------------------------------------------------------------------------
struct K1Smem {
    union {
        float red[4][6][256];          // gemm partials (4 c-quarters)
        float brow[31][258];           // bias rows (written after red consumed)
    } u;
    float tab2[64];                    // rpb gathered * log2e
    float ks_[2][TOK];                 // k * scale*log2e (+bias)
    float vs_[2][TOK];                 // v (+bias)
    float qs_[2][TOK];                 // q (+bias)
    float lpart[2][TOK], apart[2][TOK];
};

__global__ __launch_bounds__(256)
void qkv_attn(const float* __restrict__ x, const float* __restrict__ qkv_w,
              const float* __restrict__ qkv_b, const float* __restrict__ rpb,
              float* __restrict__ aout)
{
    __shared__ K1Smem sm;
    const int t    = threadIdx.x;
    const int d0   = blockIdx.x * 2;
    const int b    = blockIdx.y;
    const int w    = t >> 6;
    const int lane = t & 63;

    // phase 0: bias table (61 values), not aliased with red
    if (t < 61) {
        const int rel = t - 30;
        sm.tab2[t] = rpb[rel < 0 ? rel + 961 : rel] * LOG2E;
    }

    // ---- GEMM phase: 6 rows x 256 g, K=512 split over 4 waves ----
    {
        const float* xb = x + (size_t)b * (KDIM * TOK);
        const int g0 = lane * 4;
        // wave-uniform weight row pointers
        const float* wp[6];
        wp[0] = qkv_w + (size_t)(d0 + 0) * KDIM;
        wp[1] = qkv_w + (size_t)(d0 + 1) * KDIM;
        wp[2] = qkv_w + (size_t)(512 + d0 + 0) * KDIM;
        wp[3] = qkv_w + (size_t)(512 + d0 + 1) * KDIM;
        wp[4] = qkv_w + (size_t)(1024 + d0 + 0) * KDIM;
        wp[5] = qkv_w + (size_t)(1024 + d0 + 1) * KDIM;

        float acc[6][4];
#pragma unroll
        for (int e = 0; e < 6; ++e)
#pragma unroll
            for (int j = 0; j < 4; ++j) acc[e][j] = 0.f;

        const int cbeg = w * 128;
#pragma unroll 1
        for (int c = cbeg; c < cbeg + 128; c += 4) {
            float4 xv[4];
#pragma unroll
            for (int u = 0; u < 4; ++u)
                xv[u] = *(const float4*)(xb + (size_t)(c + u) * TOK + g0);
#pragma unroll
            for (int u = 0; u < 4; ++u) {
#pragma unroll
                for (int e = 0; e < 6; ++e) {
                    const float wv = wp[e][c + u];   // wave-uniform -> s_load
                    acc[e][0] = fmaf(wv, xv[u].x, acc[e][0]);
                    acc[e][1] = fmaf(wv, xv[u].y, acc[e][1]);
                    acc[e][2] = fmaf(wv, xv[u].z, acc[e][2]);
                    acc[e][3] = fmaf(wv, xv[u].w, acc[e][3]);
                }
            }
        }
#pragma unroll
        for (int e = 0; e < 6; ++e)
            *(float4*)&sm.u.red[w][e][g0] = make_float4(acc[e][0], acc[e][1],
                                                        acc[e][2], acc[e][3]);
    }
    __syncthreads();

    // ---- reduce 4 c-quarters + bias/scale -> ks_/vs_/qs_ ----
    {
#pragma unroll
        for (int e = 0; e < 6; ++e) {
            const float v = sm.u.red[0][e][t] + sm.u.red[1][e][t] +
                            sm.u.red[2][e][t] + sm.u.red[3][e][t];
            if (e < 2)      sm.qs_[e][t] = v + qkv_b[d0 + e];
            else if (e < 4) sm.ks_[e - 2][t] = (v + qkv_b[512 + d0 + e - 2]) *
                                               (SCALE * LOG2E);
            else            sm.vs_[e - 4][t] = v + qkv_b[1024 + d0 + e - 4];
        }
    }
    __syncthreads();

    // ---- brow fill (red region is dead now) ----
    {
        const int rg = ((t >> 4) & 15) + (t & 15);
#pragma unroll 1
        for (int it = 0; it < 31; ++it)
            sm.u.brow[it][t] = sm.tab2[it - rg + 30];
    }
    __syncthreads();

    // ---- attention main loop (R3 structure) ----
    const int dl  = w & 1;
    const int gh  = w >> 1;
    const int qi  = ((lane & 15) << 2) | (lane >> 4);  // bit-swizzled h-quad
    const int h0  = qi * 4;
    const int rh0 = (qi >> 2) + 4 * (qi & 3);          // r(h0); r(h0+r)=rh0+r

    float q[4];
    {
        const float4 q4 = *(const float4*)&sm.qs_[dl][h0];
        q[0] = q4.x; q[1] = q4.y; q[2] = q4.z; q[3] = q4.w;
    }

    float l[4]  = {0.f, 0.f, 0.f, 0.f};
    float am[4] = {0.f, 0.f, 0.f, 0.f};
    const int pbeg = gh * 128;
#pragma unroll 2
    for (int p = pbeg; p < pbeg + 128; p += 4) {
        const float4 k4 = *(const float4*)&sm.ks_[dl][p];   // wave-uniform
        const float4 v4 = *(const float4*)&sm.vs_[dl][p];
#pragma unroll
        for (int r = 0; r < 4; ++r) {
            const float2 b01 = *(const float2*)&sm.u.brow[rh0 + r][p];
            const float2 b23 = *(const float2*)&sm.u.brow[rh0 + r][p + 2];
            float e;
            e = EXP2(fmaf(q[r], k4.x, b01.x)); l[r] += e; am[r] = fmaf(e, v4.x, am[r]);
            e = EXP2(fmaf(q[r], k4.y, b01.y)); l[r] += e; am[r] = fmaf(e, v4.y, am[r]);
            e = EXP2(fmaf(q[r], k4.z, b23.x)); l[r] += e; am[r] = fmaf(e, v4.z, am[r]);
            e = EXP2(fmaf(q[r], k4.w, b23.y)); l[r] += e; am[r] = fmaf(e, v4.w, am[r]);
        }
    }

    if (gh == 1) {
        *(float4*)&sm.lpart[dl][h0] = make_float4(l[0], l[1], l[2], l[3]);
        *(float4*)&sm.apart[dl][h0] = make_float4(am[0], am[1], am[2], am[3]);
    }
    __syncthreads();
    if (gh == 0) {
        const float4 lo = *(const float4*)&sm.lpart[dl][h0];
        const float4 ao = *(const float4*)&sm.apart[dl][h0];
        float4 o4;
        o4.x = (am[0] + ao.x) / (l[0] + lo.x);
        o4.y = (am[1] + ao.y) / (l[1] + lo.y);
        o4.z = (am[2] + ao.z) / (l[2] + lo.z);
        o4.w = (am[3] + ao.w) / (l[3] + lo.w);
        *(float4*)(aout + ((size_t)b * 512 + d0 + dl) * TOK + h0) = o4;
    }
}

// ---------------------------------------------------------------------------
// K2: fused proj-gemm + bias. Block (ot, b): out rows o0..o0+3. 256 threads.
// Wave w owns c-quarter; lane owns g-quad. LDS reduce, then thread t writes
// (o0+e, g=t) for e=0..3 directly to d_out. No projp intermediate.
// ---------------------------------------------------------------------------
__global__ __launch_bounds__(256)
void proj_fused(const float* __restrict__ aout, const float* __restrict__ proj_w,
                const float* __restrict__ proj_b, float* __restrict__ out)
{
    __shared__ float sred[4][4][256];   // 16 KB
    const int t    = threadIdx.x;
    const int o0   = blockIdx.x * 4;
    const int b    = blockIdx.y;
    const int w    = t >> 6;
    const int g0   = (t & 63) * 4;

    const float* ab = aout + (size_t)b * (KDIM * TOK);
    const float* wp[4];
#pragma unroll
    for (int e = 0; e < 4; ++e)
        wp[e] = proj_w + (size_t)(o0 + e) * KDIM;

    float acc[4][4];
#pragma unroll
    for (int e = 0; e < 4; ++e)
#pragma unroll
        for (int j = 0; j < 4; ++j) acc[e][j] = 0.f;

    const int cbeg = w * 128;
#pragma unroll 1
    for (int c = cbeg; c < cbeg + 128; c += 4) {
        float4 av[4];
#pragma unroll
        for (int u = 0; u < 4; ++u)
            av[u] = *(const float4*)(ab + (size_t)(c + u) * TOK + g0);
#pragma unroll
        for (int u = 0; u < 4; ++u) {
#pragma unroll
            for (int e = 0; e < 4; ++e) {
                const float wv = wp[e][c + u];     // wave-uniform -> s_load
                acc[e][0] = fmaf(wv, av[u].x, acc[e][0]);
                acc[e][1] = fmaf(wv, av[u].y, acc[e][1]);
                acc[e][2] = fmaf(wv, av[u].z, acc[e][2]);
                acc[e][3] = fmaf(wv, av[u].w, acc[e][3]);
            }
        }
    }
#pragma unroll
    for (int e = 0; e < 4; ++e)
        *(float4*)&sred[w][e][g0] = make_float4(acc[e][0], acc[e][1],
                                                acc[e][2], acc[e][3]);
    __syncthreads();

#pragma unroll
    for (int e = 0; e < 4; ++e) {
        const float v = sred[0][e][t] + sred[1][e][t] +
                        sred[2][e][t] + sred[3][e][t] + proj_b[o0 + e];
        out[((size_t)b * 512 + o0 + e) * TOK + t] = v;
    }
}

// ---------------------------------------------------------------------------
extern "C" void kernel_launch(void* const* d_in, const int* in_sizes, int n_in,
                              void* d_out, int out_size, void* d_ws, size_t ws_size,
                              hipStream_t stream)
{
    const float* x      = (const float*)d_in[0];   // [2][512][256]
    const float* qkv_w  = (const float*)d_in[1];   // [1536][512]
    const float* qkv_b  = (const float*)d_in[2];   // [1536]
    const float* proj_w = (const float*)d_in[3];   // [512][512]
    const float* proj_b = (const float*)d_in[4];   // [512]
    const float* rpb    = (const float*)d_in[5];   // [961]
    float* out  = (float*)d_out;                   // [2][512][256]
    float* aout = (float*)d_ws;                    // 262,144 floats (1 MB)

    // K1: fused qkv + attention. grid (d-pairs=256, b=2) = 512 blocks (2/CU)
    qkv_attn<<<dim3(256, 2), 256, 0, stream>>>(x, qkv_w, qkv_b, rpb, aout);

    // K2: fused proj + bias. grid (o-tiles=128, b=2) = 256 blocks (1/CU)
    proj_fused<<<dim3(128, 2), 256, 0, stream>>>(aout, proj_w, proj_b, out);
}